// Round 1
// baseline (1717.929 us; speedup 1.0000x reference)
//
#include <hip/hip_runtime.h>
#include <cstdint>

// ---------- helpers ----------
typedef __attribute__((ext_vector_type(8))) short short8;   // 8 x bf16 (4 VGPRs)
typedef __attribute__((ext_vector_type(4))) float f32x4;

__device__ __forceinline__ float b2f(unsigned short u) {
    return __uint_as_float(((unsigned int)u) << 16);
}
__device__ __forceinline__ unsigned short f2b(float f) {   // RNE f32->bf16
    unsigned int u = __float_as_uint(f);
    u += 0x7FFFu + ((u >> 16) & 1u);
    return (unsigned short)(u >> 16);
}

// ---------- transpose + fp32->bf16 convert: w[K][N] -> wT[N][K] ----------
__global__ __launch_bounds__(256) void k_transpose_bf16(
        const float* __restrict__ w, unsigned short* __restrict__ wT, int K, int N) {
    __shared__ float tile[32][33];
    int n0 = blockIdx.x * 32, k0 = blockIdx.y * 32;
    int tx = threadIdx.x, ty = threadIdx.y;   // block (32,8)
#pragma unroll
    for (int i = 0; i < 4; i++)
        tile[ty + 8 * i][tx] = w[(size_t)(k0 + ty + 8 * i) * N + n0 + tx];
    __syncthreads();
#pragma unroll
    for (int i = 0; i < 4; i++)
        wT[(size_t)(n0 + ty + 8 * i) * K + k0 + tx] = f2b(tile[tx][ty + 8 * i]);
}

// ---------- layernorm (fp32 in, bf16 out), one row (C=1024) per block ----------
__global__ __launch_bounds__(256) void k_layernorm(
        const float* __restrict__ x, const float* __restrict__ w,
        unsigned short* __restrict__ out) {
    int row = blockIdx.x, tid = threadIdx.x;
    const float4* xr = (const float4*)(x + (size_t)row * 1024);
    float4 v = xr[tid];
    float s  = v.x + v.y + v.z + v.w;
    float ss = v.x * v.x + v.y * v.y + v.z * v.z + v.w * v.w;
#pragma unroll
    for (int off = 32; off >= 1; off >>= 1) {
        s  += __shfl_down(s, off);
        ss += __shfl_down(ss, off);
    }
    __shared__ float red[10];
    if ((tid & 63) == 0) { red[tid >> 6] = s; red[4 + (tid >> 6)] = ss; }
    __syncthreads();
    if (tid == 0) {
        float S  = red[0] + red[1] + red[2] + red[3];
        float SS = red[4] + red[5] + red[6] + red[7];
        float mu  = S * (1.0f / 1024.0f);
        float var = SS * (1.0f / 1024.0f) - mu * mu;
        red[8] = mu; red[9] = rsqrtf(var + 1e-5f);
    }
    __syncthreads();
    float mu = red[8], rs = red[9];
    float4 wv = ((const float4*)w)[tid];
    ushort4 pk;
    pk.x = f2b((v.x - mu) * rs * wv.x);
    pk.y = f2b((v.y - mu) * rs * wv.y);
    pk.z = f2b((v.z - mu) * rs * wv.z);
    pk.w = f2b((v.w - mu) * rs * wv.w);
    *(ushort4*)(out + (size_t)row * 1024 + tid * 4) = pk;
}

// ---------- bf16 MFMA GEMM: C[M][N] = A[M][K] @ BT[N][K]^T (+ epilogue) ----------
// EPI: 0 = store f32, 1 = store bf16, 2 = RES + acc -> f32, 3 = gelu(acc) -> bf16
template <int EPI>
__global__ __launch_bounds__(256) void k_gemm_bt(
        const unsigned short* __restrict__ A, const unsigned short* __restrict__ BT,
        const float* __restrict__ RES, void* __restrict__ OUT,
        int M, int N, int K) {
    // 128x128 block tile, 4 waves each doing 64x64 (4x4 MFMA 16x16x32 tiles)
    __shared__ unsigned short As[128][40];   // stride 40 bf16 = 80B: balanced banks
    __shared__ unsigned short Bs[128][40];
    int tid  = threadIdx.x;
    int lane = tid & 63, wave = tid >> 6;
    int quad = lane >> 4, qr = lane & 15;
    int wm = wave >> 1, wn = wave & 1;
    int m0 = blockIdx.y * 128, n0 = blockIdx.x * 128;
    f32x4 acc[4][4] = {};
    for (int k0 = 0; k0 < K; k0 += 32) {
#pragma unroll
        for (int r = 0; r < 2; r++) {           // stage 128x32 A and BT slabs
            int c = r * 256 + tid;
            int row = c >> 2, c8 = c & 3;
            *(uint4*)&As[row][c8 * 8] = *(const uint4*)&A [(size_t)(m0 + row) * K + k0 + c8 * 8];
            *(uint4*)&Bs[row][c8 * 8] = *(const uint4*)&BT[(size_t)(n0 + row) * K + k0 + c8 * 8];
        }
        __syncthreads();
        short8 af[4], bfr[4];
#pragma unroll
        for (int i = 0; i < 4; i++) af[i]  = *(const short8*)&As[wm * 64 + i * 16 + qr][quad * 8];
#pragma unroll
        for (int j = 0; j < 4; j++) bfr[j] = *(const short8*)&Bs[wn * 64 + j * 16 + qr][quad * 8];
#pragma unroll
        for (int i = 0; i < 4; i++)
#pragma unroll
            for (int j = 0; j < 4; j++)
                acc[i][j] = __builtin_amdgcn_mfma_f32_16x16x32_bf16(af[i], bfr[j], acc[i][j], 0, 0, 0);
        __syncthreads();
    }
    // epilogue: C/D layout col=lane&15, row=quad*4+reg (m89/m91-verified)
#pragma unroll
    for (int i = 0; i < 4; i++) {
#pragma unroll
        for (int j = 0; j < 4; j++) {
#pragma unroll
            for (int r = 0; r < 4; r++) {
                int row = m0 + wm * 64 + i * 16 + quad * 4 + r;
                int col = n0 + wn * 64 + j * 16 + qr;
                size_t idx = (size_t)row * N + col;
                float v = acc[i][j][r];
                if (EPI == 0)      ((float*)OUT)[idx] = v;
                else if (EPI == 1) ((unsigned short*)OUT)[idx] = f2b(v);
                else if (EPI == 2) ((float*)OUT)[idx] = RES[idx] + v;
                else {
                    float g = 0.5f * v * (1.0f + erff(v * 0.70710678118f));
                    ((unsigned short*)OUT)[idx] = f2b(g);
                }
            }
        }
    }
}

// ---------- causal flash attention, fp32 vector math ----------
// qkv: bf16 [4096][3072] (q|k|v each 1024 cols, head h dims h*64..h*64+63)
// out: bf16 [4096][1024]
__global__ __launch_bounds__(256) void k_attn(
        const unsigned short* __restrict__ qkv, unsigned short* __restrict__ out) {
    __shared__ unsigned short Qs[64][72];   // bf16, stride 72 (144B, 16B-aligned)
    __shared__ float Ks[64][68];            // +4 float pad: conflict-free column reads
    __shared__ float Vs[64][68];
    __shared__ float Ps[4][16][68];         // per-wave P tile [16 q][64 k]
    int tid = threadIdx.x;
    int h = blockIdx.y, qb = blockIdx.x;
    int q0 = qb * 64;
    int wave = tid >> 6, lane = tid & 63, qi = lane & 15, grp = lane >> 4;
    int q_global = q0 + wave * 16 + qi;

    {   // stage Q tile (raw bf16 copy; scores scaled later)
        int row = tid >> 2, c0 = (tid & 3) * 16;
        const uint4* src = (const uint4*)&qkv[(size_t)(q0 + row) * 3072 + h * 64 + c0];
        *(uint4*)&Qs[row][c0]     = src[0];
        *(uint4*)&Qs[row][c0 + 8] = src[1];
    }
    float m_i = -__builtin_inff(), l_i = 0.0f;
    float O[16];
#pragma unroll
    for (int d = 0; d < 16; d++) O[d] = 0.0f;

    for (int kb = 0; kb <= qb; kb++) {
        __syncthreads();   // prev iter's LDS reads done (also covers Q staging at kb=0)
        {   // stage K,V block (bf16 -> f32)
            int row = tid >> 2, c0 = (tid & 3) * 16;
            size_t base = (size_t)(kb * 64 + row) * 3072 + h * 64 + c0;
            uint4 ka = *(const uint4*)&qkv[base + 1024];
            uint4 kc = *(const uint4*)&qkv[base + 1024 + 8];
            uint4 va = *(const uint4*)&qkv[base + 2048];
            uint4 vc = *(const uint4*)&qkv[base + 2048 + 8];
            float* kd = &Ks[row][c0];
            kd[0] = b2f(ka.x & 0xFFFF); kd[1] = b2f(ka.x >> 16);
            kd[2] = b2f(ka.y & 0xFFFF); kd[3] = b2f(ka.y >> 16);
            kd[4] = b2f(ka.z & 0xFFFF); kd[5] = b2f(ka.z >> 16);
            kd[6] = b2f(ka.w & 0xFFFF); kd[7] = b2f(ka.w >> 16);
            kd[8]  = b2f(kc.x & 0xFFFF); kd[9]  = b2f(kc.x >> 16);
            kd[10] = b2f(kc.y & 0xFFFF); kd[11] = b2f(kc.y >> 16);
            kd[12] = b2f(kc.z & 0xFFFF); kd[13] = b2f(kc.z >> 16);
            kd[14] = b2f(kc.w & 0xFFFF); kd[15] = b2f(kc.w >> 16);
            float* vd = &Vs[row][c0];
            vd[0] = b2f(va.x & 0xFFFF); vd[1] = b2f(va.x >> 16);
            vd[2] = b2f(va.y & 0xFFFF); vd[3] = b2f(va.y >> 16);
            vd[4] = b2f(va.z & 0xFFFF); vd[5] = b2f(va.z >> 16);
            vd[6] = b2f(va.w & 0xFFFF); vd[7] = b2f(va.w >> 16);
            vd[8]  = b2f(vc.x & 0xFFFF); vd[9]  = b2f(vc.x >> 16);
            vd[10] = b2f(vc.y & 0xFFFF); vd[11] = b2f(vc.y >> 16);
            vd[12] = b2f(vc.z & 0xFFFF); vd[13] = b2f(vc.z >> 16);
            vd[14] = b2f(vc.w & 0xFFFF); vd[15] = b2f(vc.w >> 16);
        }
        __syncthreads();
        // ---- S = Q K^T: lane (qi, grp) computes 16 keys (grp-staggered for banks)
        float s[16];
#pragma unroll
        for (int j = 0; j < 16; j++) s[j] = 0.0f;
#pragma unroll
        for (int d8 = 0; d8 < 8; d8++) {
            short8 q8 = *(const short8*)&Qs[wave * 16 + qi][d8 * 8];
            float qf[8];
#pragma unroll
            for (int b = 0; b < 8; b++) qf[b] = b2f((unsigned short)q8[b]);
#pragma unroll
            for (int j = 0; j < 16; j++) {
                int jj = (j + grp * 4) & 15;
                const float* kr = &Ks[grp * 16 + jj][d8 * 8];
                float4 k1 = *(const float4*)kr;
                float4 k2 = *(const float4*)(kr + 4);
                s[j] += qf[0] * k1.x + qf[1] * k1.y + qf[2] * k1.z + qf[3] * k1.w
                      + qf[4] * k2.x + qf[5] * k2.y + qf[6] * k2.z + qf[7] * k2.w;
            }
        }
        // ---- causal mask + online softmax (row state replicated over 4 grp lanes)
        float mblk = -__builtin_inff();
#pragma unroll
        for (int j = 0; j < 16; j++) {
            int jj = (j + grp * 4) & 15;
            int kidx = kb * 64 + grp * 16 + jj;
            s[j] = (kidx <= q_global) ? s[j] * 0.125f : -__builtin_inff();
            mblk = fmaxf(mblk, s[j]);
        }
        mblk = fmaxf(mblk, __shfl_xor(mblk, 16));
        mblk = fmaxf(mblk, __shfl_xor(mblk, 32));
        float mnew  = fmaxf(m_i, mblk);
        float alpha = __expf(m_i - mnew);   // first iter: exp(-inf)=0
        float lblk = 0.0f;
#pragma unroll
        for (int j = 0; j < 16; j++) {
            int jj = (j + grp * 4) & 15;
            float p = __expf(s[j] - mnew);  // masked -> 0
            Ps[wave][qi][grp * 16 + jj] = p;
            lblk += p;
        }
        lblk += __shfl_xor(lblk, 16);
        lblk += __shfl_xor(lblk, 32);
        l_i = l_i * alpha + lblk;
        m_i = mnew;
#pragma unroll
        for (int d = 0; d < 16; d++) O[d] *= alpha;
        // ---- O += P V: lane (qi, grp=dim-group) owns dims grp*16..grp*16+15
#pragma unroll 8
        for (int kk = 0; kk < 64; kk++) {
            float p = Ps[wave][qi][kk];
            const float* vr = &Vs[kk][grp * 16];
            float4 v0 = *(const float4*)vr;
            float4 v1 = *(const float4*)(vr + 4);
            float4 v2 = *(const float4*)(vr + 8);
            float4 v3 = *(const float4*)(vr + 12);
            O[0]  += p * v0.x; O[1]  += p * v0.y; O[2]  += p * v0.z; O[3]  += p * v0.w;
            O[4]  += p * v1.x; O[5]  += p * v1.y; O[6]  += p * v1.z; O[7]  += p * v1.w;
            O[8]  += p * v2.x; O[9]  += p * v2.y; O[10] += p * v2.z; O[11] += p * v2.w;
            O[12] += p * v3.x; O[13] += p * v3.y; O[14] += p * v3.z; O[15] += p * v3.w;
        }
    }
    float inv = 1.0f / l_i;
    unsigned short* orow = out + (size_t)q_global * 1024 + h * 64 + grp * 16;
    ushort4 pk;
    pk.x = f2b(O[0] * inv);  pk.y = f2b(O[1] * inv);
    pk.z = f2b(O[2] * inv);  pk.w = f2b(O[3] * inv);
    *(ushort4*)(orow + 0) = pk;
    pk.x = f2b(O[4] * inv);  pk.y = f2b(O[5] * inv);
    pk.z = f2b(O[6] * inv);  pk.w = f2b(O[7] * inv);
    *(ushort4*)(orow + 4) = pk;
    pk.x = f2b(O[8] * inv);  pk.y = f2b(O[9] * inv);
    pk.z = f2b(O[10] * inv); pk.w = f2b(O[11] * inv);
    *(ushort4*)(orow + 8) = pk;
    pk.x = f2b(O[12] * inv); pk.y = f2b(O[13] * inv);
    pk.z = f2b(O[14] * inv); pk.w = f2b(O[15] * inv);
    *(ushort4*)(orow + 12) = pk;
}

// ---------- launch ----------
extern "C" void kernel_launch(void* const* d_in, const int* in_sizes, int n_in,
                              void* d_out, int out_size, void* d_ws, size_t ws_size,
                              hipStream_t stream) {
    const float* x      = (const float*)d_in[0];   // [4096][1024]
    const float* w_qkv  = (const float*)d_in[1];   // [1024][3072]
    const float* w_attn = (const float*)d_in[2];   // [1024][1024]
    const float* w_fc   = (const float*)d_in[3];   // [1024][4096]
    const float* w_mlp  = (const float*)d_in[4];   // [4096][1024]
    const float* ln1w   = (const float*)d_in[5];
    const float* ln2w   = (const float*)d_in[6];

    char* ws = (char*)d_ws;   // total use: 112 MB
    unsigned short* h      = (unsigned short*)(ws + 0);          //  8 MB [4096][1024]
    unsigned short* wqkvT  = (unsigned short*)(ws + 8388608);    //  6 MB [3072][1024]
    unsigned short* wattnT = (unsigned short*)(ws + 14680064);   //  2 MB [1024][1024]
    unsigned short* wfcT   = (unsigned short*)(ws + 16777216);   //  8 MB [4096][1024]
    unsigned short* wmlpT  = (unsigned short*)(ws + 25165824);   //  8 MB [1024][4096]
    unsigned short* qkv    = (unsigned short*)(ws + 33554432);   // 24 MB [4096][3072]
    unsigned short* attno  = (unsigned short*)(ws + 58720256);   //  8 MB [4096][1024]
    float*          x2     = (float*)(ws + 67108864);            // 16 MB [4096][1024]
    unsigned short* fcact  = (unsigned short*)(ws + 83886080);   // 32 MB [4096][4096]
    float* outF = (float*)d_out;

    dim3 tb(32, 8);
    k_transpose_bf16<<<dim3(96, 32),  tb, 0, stream>>>(w_qkv,  wqkvT,  1024, 3072);
    k_transpose_bf16<<<dim3(32, 32),  tb, 0, stream>>>(w_attn, wattnT, 1024, 1024);
    k_transpose_bf16<<<dim3(128, 32), tb, 0, stream>>>(w_fc,   wfcT,   1024, 4096);
    k_transpose_bf16<<<dim3(32, 128), tb, 0, stream>>>(w_mlp,  wmlpT,  4096, 1024);

    k_layernorm<<<4096, 256, 0, stream>>>(x, ln1w, h);
    k_gemm_bt<1><<<dim3(24, 32), 256, 0, stream>>>(h, wqkvT, nullptr, qkv, 4096, 3072, 1024);
    k_attn<<<dim3(64, 16), 256, 0, stream>>>(qkv, attno);
    k_gemm_bt<2><<<dim3(8, 32),  256, 0, stream>>>(attno, wattnT, x, x2, 4096, 1024, 1024);
    k_layernorm<<<4096, 256, 0, stream>>>(x2, ln2w, h);
    k_gemm_bt<3><<<dim3(32, 32), 256, 0, stream>>>(h, wfcT, nullptr, fcact, 4096, 4096, 1024);
    k_gemm_bt<2><<<dim3(8, 32),  256, 0, stream>>>(fcact, wmlpT, x2, outF, 4096, 1024, 4096);
}

// Round 3
// 538.160 us; speedup vs baseline: 3.1922x; 3.1922x over previous
//
#include <hip/hip_runtime.h>
#include <cstdint>

// ---------- helpers ----------
typedef __attribute__((ext_vector_type(8))) short short8;   // 8 x bf16 (4 VGPRs)
typedef __attribute__((ext_vector_type(4))) float f32x4;

__device__ __forceinline__ float b2f(unsigned short u) {
    return __uint_as_float(((unsigned int)u) << 16);
}
__device__ __forceinline__ unsigned short f2b(float f) {   // RNE f32->bf16
    unsigned int u = __float_as_uint(f);
    u += 0x7FFFu + ((u >> 16) & 1u);
    return (unsigned short)(u >> 16);
}

// ---------- transpose + fp32->bf16 convert: w[K][N] -> wT[N][K] ----------
__global__ __launch_bounds__(256) void k_transpose_bf16(
        const float* __restrict__ w, unsigned short* __restrict__ wT, int K, int N) {
    __shared__ float tile[32][33];
    int n0 = blockIdx.x * 32, k0 = blockIdx.y * 32;
    int tx = threadIdx.x, ty = threadIdx.y;   // block (32,8)
#pragma unroll
    for (int i = 0; i < 4; i++)
        tile[ty + 8 * i][tx] = w[(size_t)(k0 + ty + 8 * i) * N + n0 + tx];
    __syncthreads();
#pragma unroll
    for (int i = 0; i < 4; i++)
        wT[(size_t)(n0 + ty + 8 * i) * K + k0 + tx] = f2b(tile[tx][ty + 8 * i]);
}

// ---------- layernorm (fp32 in, bf16 out), one row (C=1024) per block ----------
__global__ __launch_bounds__(256) void k_layernorm(
        const float* __restrict__ x, const float* __restrict__ w,
        unsigned short* __restrict__ out) {
    int row = blockIdx.x, tid = threadIdx.x;
    const float4* xr = (const float4*)(x + (size_t)row * 1024);
    float4 v = xr[tid];
    float s  = v.x + v.y + v.z + v.w;
    float ss = v.x * v.x + v.y * v.y + v.z * v.z + v.w * v.w;
#pragma unroll
    for (int off = 32; off >= 1; off >>= 1) {
        s  += __shfl_down(s, off);
        ss += __shfl_down(ss, off);
    }
    __shared__ float red[10];
    if ((tid & 63) == 0) { red[tid >> 6] = s; red[4 + (tid >> 6)] = ss; }
    __syncthreads();
    if (tid == 0) {
        float S  = red[0] + red[1] + red[2] + red[3];
        float SS = red[4] + red[5] + red[6] + red[7];
        float mu  = S * (1.0f / 1024.0f);
        float var = SS * (1.0f / 1024.0f) - mu * mu;
        red[8] = mu; red[9] = rsqrtf(var + 1e-5f);
    }
    __syncthreads();
    float mu = red[8], rs = red[9];
    float4 wv = ((const float4*)w)[tid];
    ushort4 pk;
    pk.x = f2b((v.x - mu) * rs * wv.x);
    pk.y = f2b((v.y - mu) * rs * wv.y);
    pk.z = f2b((v.z - mu) * rs * wv.z);
    pk.w = f2b((v.w - mu) * rs * wv.w);
    *(ushort4*)(out + (size_t)row * 1024 + tid * 4) = pk;
}

// ---------- bf16 MFMA GEMM: C[M][N] = A[M][K] @ BT[N][K]^T (+ epilogue) ----------
// EPI: 0 = store f32, 1 = store bf16, 2 = RES + acc -> f32, 3 = gelu(acc) -> bf16
template <int EPI>
__global__ __launch_bounds__(256) void k_gemm_bt(
        const unsigned short* __restrict__ A, const unsigned short* __restrict__ BT,
        const float* __restrict__ RES, void* __restrict__ OUT,
        int M, int N, int K) {
    __shared__ unsigned short As[128][40];
    __shared__ unsigned short Bs[128][40];
    int tid  = threadIdx.x;
    int lane = tid & 63, wave = tid >> 6;
    int quad = lane >> 4, qr = lane & 15;
    int wm = wave >> 1, wn = wave & 1;
    int m0 = blockIdx.y * 128, n0 = blockIdx.x * 128;
    f32x4 acc[4][4] = {};
    for (int k0 = 0; k0 < K; k0 += 32) {
#pragma unroll
        for (int r = 0; r < 2; r++) {
            int c = r * 256 + tid;
            int row = c >> 2, c8 = c & 3;
            *(uint4*)&As[row][c8 * 8] = *(const uint4*)&A [(size_t)(m0 + row) * K + k0 + c8 * 8];
            *(uint4*)&Bs[row][c8 * 8] = *(const uint4*)&BT[(size_t)(n0 + row) * K + k0 + c8 * 8];
        }
        __syncthreads();
        short8 af[4], bfr[4];
#pragma unroll
        for (int i = 0; i < 4; i++) af[i]  = *(const short8*)&As[wm * 64 + i * 16 + qr][quad * 8];
#pragma unroll
        for (int j = 0; j < 4; j++) bfr[j] = *(const short8*)&Bs[wn * 64 + j * 16 + qr][quad * 8];
#pragma unroll
        for (int i = 0; i < 4; i++)
#pragma unroll
            for (int j = 0; j < 4; j++)
                acc[i][j] = __builtin_amdgcn_mfma_f32_16x16x32_bf16(af[i], bfr[j], acc[i][j], 0, 0, 0);
        __syncthreads();
    }
#pragma unroll
    for (int i = 0; i < 4; i++) {
#pragma unroll
        for (int j = 0; j < 4; j++) {
#pragma unroll
            for (int r = 0; r < 4; r++) {
                int row = m0 + wm * 64 + i * 16 + quad * 4 + r;
                int col = n0 + wn * 64 + j * 16 + qr;
                size_t idx = (size_t)row * N + col;
                float v = acc[i][j][r];
                if (EPI == 0)      ((float*)OUT)[idx] = v;
                else if (EPI == 1) ((unsigned short*)OUT)[idx] = f2b(v);
                else if (EPI == 2) ((float*)OUT)[idx] = RES[idx] + v;
                else {
                    float g = 0.5f * v * (1.0f + erff(v * 0.70710678118f));
                    ((unsigned short*)OUT)[idx] = f2b(g);
                }
            }
        }
    }
}

// ---------- MFMA causal flash attention (self-contained: V transposed in-LDS) ----
// qkv bf16 [4096][3072] (q|k|v blocks of 1024 cols), out bf16 [4096][1024]
// Block: one head, 64 q-rows; 4 waves x 16 q-rows. 16x16x32 bf16 MFMA.
__global__ __launch_bounds__(256) void k_attn(
        const unsigned short* __restrict__ qkv, unsigned short* __restrict__ out) {
    __shared__ unsigned short Qs[64][72];
    __shared__ unsigned short Ks[64][72];
    __shared__ unsigned short Vt[64][72];       // [dim][key] — transposed at staging
    __shared__ unsigned short Ps[4][16][72];    // per wave [q][key]

    int l = blockIdx.x;                 // 0..1023
    int x = l & 63, y = l >> 6;
    int h = y;
    int qb = 63 - ((x + ((y >> 2) << 4)) & 63);   // big blocks first; CU-mixed sizes
    int q0 = qb * 64;

    int tid = threadIdx.x;
    int wave = tid >> 6, lane = tid & 63;
    int lane16 = lane & 15, quad = lane >> 4;
    int srow = tid >> 2, sc0 = (tid & 3) * 16;

    // stage Q tile
    {
        size_t base = (size_t)(q0 + srow) * 3072 + h * 64 + sc0;
        *(uint4*)&Qs[srow][sc0]     = *(const uint4*)&qkv[base];
        *(uint4*)&Qs[srow][sc0 + 8] = *(const uint4*)&qkv[base + 8];
    }

    f32x4 Oacc[4] = {};                 // [d-tile]; lane holds O[q=quad*4+r][d=dt*16+lane16]
    float m_i[4], l_i[4];
#pragma unroll
    for (int r = 0; r < 4; r++) { m_i[r] = -__builtin_inff(); l_i[r] = 0.0f; }

    for (int kb = 0; kb <= qb; kb++) {
        __syncthreads();   // prev-iter LDS reads done (covers Q staging at kb=0)
        {   // stage K block (row-major, coalesced b128)
            size_t kbase = (size_t)(kb * 64 + srow) * 3072 + 1024 + h * 64 + sc0;
            *(uint4*)&Ks[srow][sc0]     = *(const uint4*)&qkv[kbase];
            *(uint4*)&Ks[srow][sc0 + 8] = *(const uint4*)&qkv[kbase + 8];
        }
        {   // stage V block TRANSPOSED: wave = dim-group, lane = key.
            // ds_write_b16 instr j: row wave*16+j, col=lane -> banks spread, ~2/dword: free.
            size_t vbase = (size_t)(kb * 64 + lane) * 3072 + 2048 + h * 64 + wave * 16;
            __align__(16) unsigned short vs[16];
            *(uint4*)&vs[0] = *(const uint4*)&qkv[vbase];
            *(uint4*)&vs[8] = *(const uint4*)&qkv[vbase + 8];
#pragma unroll
            for (int j = 0; j < 16; j++) Vt[wave * 16 + j][lane] = vs[j];
        }
        __syncthreads();

        // ---- S = Q K^T  (16q x 64k per wave) ----
        f32x4 sacc[4] = {};
        short8 aq0 = *(const short8*)&Qs[wave * 16 + lane16][quad * 8];
        short8 aq1 = *(const short8*)&Qs[wave * 16 + lane16][32 + quad * 8];
#pragma unroll
        for (int kt = 0; kt < 4; kt++) {
            short8 bk0 = *(const short8*)&Ks[kt * 16 + lane16][quad * 8];
            short8 bk1 = *(const short8*)&Ks[kt * 16 + lane16][32 + quad * 8];
            sacc[kt] = __builtin_amdgcn_mfma_f32_16x16x32_bf16(aq0, bk0, sacc[kt], 0, 0, 0);
            sacc[kt] = __builtin_amdgcn_mfma_f32_16x16x32_bf16(aq1, bk1, sacc[kt], 0, 0, 0);
        }

        // ---- online softmax (C-layout: lane has S[q=quad*4+r][key=kt*16+lane16]) ----
#pragma unroll
        for (int r = 0; r < 4; r++) {
            int qrow = q0 + wave * 16 + quad * 4 + r;
            float sv[4], mx = -__builtin_inff();
#pragma unroll
            for (int kt = 0; kt < 4; kt++) {
                int key = kb * 64 + kt * 16 + lane16;
                sv[kt] = (key <= qrow) ? sacc[kt][r] * 0.125f : -__builtin_inff();
                mx = fmaxf(mx, sv[kt]);
            }
            mx = fmaxf(mx, __shfl_xor(mx, 1));
            mx = fmaxf(mx, __shfl_xor(mx, 2));
            mx = fmaxf(mx, __shfl_xor(mx, 4));
            mx = fmaxf(mx, __shfl_xor(mx, 8));
            float mn = fmaxf(m_i[r], mx);
            float alpha = __expf(m_i[r] - mn);   // first iter: exp(-inf)=0
            float ls = 0.0f;
#pragma unroll
            for (int kt = 0; kt < 4; kt++) {
                float p = __expf(sv[kt] - mn);   // masked -> 0
                ls += p;
                Ps[wave][quad * 4 + r][kt * 16 + lane16] = f2b(p);
            }
            ls += __shfl_xor(ls, 1);
            ls += __shfl_xor(ls, 2);
            ls += __shfl_xor(ls, 4);
            ls += __shfl_xor(ls, 8);
            l_i[r] = l_i[r] * alpha + ls;
            m_i[r] = mn;
#pragma unroll
            for (int dt = 0; dt < 4; dt++) Oacc[dt][r] *= alpha;
        }

        __syncthreads();   // Ps writes visible before PV reads (no wave-sync reliance)

        // ---- O += P V  (A=P from LDS in A-layout; B=V^T rows) ----
#pragma unroll
        for (int s = 0; s < 2; s++) {
            short8 ap = *(const short8*)&Ps[wave][lane16][s * 32 + quad * 8];
#pragma unroll
            for (int dt = 0; dt < 4; dt++) {
                short8 bv = *(const short8*)&Vt[dt * 16 + lane16][s * 32 + quad * 8];
                Oacc[dt] = __builtin_amdgcn_mfma_f32_16x16x32_bf16(ap, bv, Oacc[dt], 0, 0, 0);
            }
        }
    }

    float invl[4];
#pragma unroll
    for (int r = 0; r < 4; r++) invl[r] = 1.0f / l_i[r];
#pragma unroll
    for (int dt = 0; dt < 4; dt++) {
#pragma unroll
        for (int r = 0; r < 4; r++) {
            int qrow = q0 + wave * 16 + quad * 4 + r;
            out[(size_t)qrow * 1024 + h * 64 + dt * 16 + lane16] = f2b(Oacc[dt][r] * invl[r]);
        }
    }
}

// ---------- launch ----------
extern "C" void kernel_launch(void* const* d_in, const int* in_sizes, int n_in,
                              void* d_out, int out_size, void* d_ws, size_t ws_size,
                              hipStream_t stream) {
    const float* x      = (const float*)d_in[0];
    const float* w_qkv  = (const float*)d_in[1];
    const float* w_attn = (const float*)d_in[2];
    const float* w_fc   = (const float*)d_in[3];
    const float* w_mlp  = (const float*)d_in[4];
    const float* ln1w   = (const float*)d_in[5];
    const float* ln2w   = (const float*)d_in[6];

    char* ws = (char*)d_ws;   // total 112 MB, no aliasing
    unsigned short* h      = (unsigned short*)(ws + 0);          //  8 MB
    unsigned short* wqkvT  = (unsigned short*)(ws + 8388608);    //  6 MB
    unsigned short* wattnT = (unsigned short*)(ws + 14680064);   //  2 MB
    unsigned short* wfcT   = (unsigned short*)(ws + 16777216);   //  8 MB
    unsigned short* wmlpT  = (unsigned short*)(ws + 25165824);   //  8 MB
    unsigned short* qkv    = (unsigned short*)(ws + 33554432);   // 24 MB
    unsigned short* attno  = (unsigned short*)(ws + 58720256);   //  8 MB
    float*          x2     = (float*)(ws + 67108864);            // 16 MB
    unsigned short* fcact  = (unsigned short*)(ws + 83886080);   // 32 MB
    float* outF = (float*)d_out;

    dim3 tb(32, 8);
    k_transpose_bf16<<<dim3(96, 32),  tb, 0, stream>>>(w_qkv,  wqkvT,  1024, 3072);
    k_transpose_bf16<<<dim3(32, 32),  tb, 0, stream>>>(w_attn, wattnT, 1024, 1024);
    k_transpose_bf16<<<dim3(128, 32), tb, 0, stream>>>(w_fc,   wfcT,   1024, 4096);
    k_transpose_bf16<<<dim3(32, 128), tb, 0, stream>>>(w_mlp,  wmlpT,  4096, 1024);

    k_layernorm<<<4096, 256, 0, stream>>>(x, ln1w, h);
    k_gemm_bt<1><<<dim3(24, 32), 256, 0, stream>>>(h, wqkvT, nullptr, qkv, 4096, 3072, 1024);
    k_attn<<<1024, 256, 0, stream>>>(qkv, attno);
    k_gemm_bt<2><<<dim3(8, 32),  256, 0, stream>>>(attno, wattnT, x, x2, 4096, 1024, 1024);
    k_layernorm<<<4096, 256, 0, stream>>>(x2, ln2w, h);
    k_gemm_bt<3><<<dim3(32, 32), 256, 0, stream>>>(h, wfcT, nullptr, fcact, 4096, 4096, 1024);
    k_gemm_bt<2><<<dim3(8, 32),  256, 0, stream>>>(fcact, wmlpT, x2, outF, 4096, 1024, 4096);
}

// Round 4
// 488.039 us; speedup vs baseline: 3.5201x; 1.1027x over previous
//
#include <hip/hip_runtime.h>
#include <cstdint>

// ---------- helpers ----------
typedef __attribute__((ext_vector_type(8))) short short8;   // 8 x bf16 (4 VGPRs)
typedef __attribute__((ext_vector_type(4))) float f32x4;

__device__ __forceinline__ float b2f(unsigned short u) {
    return __uint_as_float(((unsigned int)u) << 16);
}
__device__ __forceinline__ unsigned short f2b(float f) {   // RNE f32->bf16
    unsigned int u = __float_as_uint(f);
    u += 0x7FFFu + ((u >> 16) & 1u);
    return (unsigned short)(u >> 16);
}

// async global->LDS, 16B per lane; LDS dest is wave-uniform base + lane*16
__device__ __forceinline__ void gload_lds16(const unsigned short* g, unsigned short* l) {
    __builtin_amdgcn_global_load_lds(
        (const __attribute__((address_space(1))) uint32_t*)g,
        (__attribute__((address_space(3))) uint32_t*)l, 16, 0, 0);
}

// ---------- transpose + fp32->bf16 convert: w[K][N] -> wT[N][K] ----------
__global__ __launch_bounds__(256) void k_transpose_bf16(
        const float* __restrict__ w, unsigned short* __restrict__ wT, int K, int N) {
    __shared__ float tile[32][33];
    int n0 = blockIdx.x * 32, k0 = blockIdx.y * 32;
    int tx = threadIdx.x, ty = threadIdx.y;   // block (32,8)
#pragma unroll
    for (int i = 0; i < 4; i++)
        tile[ty + 8 * i][tx] = w[(size_t)(k0 + ty + 8 * i) * N + n0 + tx];
    __syncthreads();
#pragma unroll
    for (int i = 0; i < 4; i++)
        wT[(size_t)(n0 + ty + 8 * i) * K + k0 + tx] = f2b(tile[tx][ty + 8 * i]);
}

// ---------- layernorm (fp32 in, bf16 out), one row (C=1024) per block ----------
__global__ __launch_bounds__(256) void k_layernorm(
        const float* __restrict__ x, const float* __restrict__ w,
        unsigned short* __restrict__ out) {
    int row = blockIdx.x, tid = threadIdx.x;
    const float4* xr = (const float4*)(x + (size_t)row * 1024);
    float4 v = xr[tid];
    float s  = v.x + v.y + v.z + v.w;
    float ss = v.x * v.x + v.y * v.y + v.z * v.z + v.w * v.w;
#pragma unroll
    for (int off = 32; off >= 1; off >>= 1) {
        s  += __shfl_down(s, off);
        ss += __shfl_down(ss, off);
    }
    __shared__ float red[10];
    if ((tid & 63) == 0) { red[tid >> 6] = s; red[4 + (tid >> 6)] = ss; }
    __syncthreads();
    if (tid == 0) {
        float S  = red[0] + red[1] + red[2] + red[3];
        float SS = red[4] + red[5] + red[6] + red[7];
        float mu  = S * (1.0f / 1024.0f);
        float var = SS * (1.0f / 1024.0f) - mu * mu;
        red[8] = mu; red[9] = rsqrtf(var + 1e-5f);
    }
    __syncthreads();
    float mu = red[8], rs = red[9];
    float4 wv = ((const float4*)w)[tid];
    ushort4 pk;
    pk.x = f2b((v.x - mu) * rs * wv.x);
    pk.y = f2b((v.y - mu) * rs * wv.y);
    pk.z = f2b((v.z - mu) * rs * wv.z);
    pk.w = f2b((v.w - mu) * rs * wv.w);
    *(ushort4*)(out + (size_t)row * 1024 + tid * 4) = pk;
}

// ---------- bf16 MFMA GEMM (m97 pattern): C = A[M][K] @ BT[N][K]^T + epilogue ----
// EPI: 0 = store f32, 1 = store bf16, 2 = RES + acc -> f32, 3 = gelu(acc) -> bf16
template <int EPI>
__global__ __launch_bounds__(256) void k_gemm_bt(
        const unsigned short* __restrict__ A, const unsigned short* __restrict__ BT,
        const float* __restrict__ RES, void* __restrict__ OUT,
        int M, int N, int K) {
    // unpadded 128x32 slabs: required by global_load_lds lane-contiguous deposit
    __shared__ __align__(16) unsigned short As[128 * 32];
    __shared__ __align__(16) unsigned short Bs[128 * 32];
    int tid  = threadIdx.x;
    int lane = tid & 63, wave = tid >> 6;
    int quad = lane >> 4, qr = lane & 15;
    int wm = wave >> 1, wn = wave & 1;
    int m0 = blockIdx.y * 128, n0 = blockIdx.x * 128;
    int lrow = lane >> 2, lcol = (lane & 3) * 8;   // lane's slab coords (16 rows x 4 col-chunks)
    f32x4 acc[4][4] = {};
    for (int k0 = 0; k0 < K; k0 += 32) {
        __syncthreads();
#pragma unroll
        for (int t = 0; t < 2; t++) {   // wave stages rows wave*32 + t*16 .. +15
            int row = wave * 32 + t * 16 + lrow;
            gload_lds16(&A [(size_t)(m0 + row) * K + k0 + lcol], &As[wave * 1024 + t * 512]);
            gload_lds16(&BT[(size_t)(n0 + row) * K + k0 + lcol], &Bs[wave * 1024 + t * 512]);
        }
        __syncthreads();   // compiler inserts vmcnt(0) drain here
        short8 af[4], bfr[4];
#pragma unroll
        for (int i = 0; i < 4; i++) af[i]  = *(const short8*)&As[(wm * 64 + i * 16 + qr) * 32 + quad * 8];
#pragma unroll
        for (int j = 0; j < 4; j++) bfr[j] = *(const short8*)&Bs[(wn * 64 + j * 16 + qr) * 32 + quad * 8];
#pragma unroll
        for (int i = 0; i < 4; i++)
#pragma unroll
            for (int j = 0; j < 4; j++)
                acc[i][j] = __builtin_amdgcn_mfma_f32_16x16x32_bf16(af[i], bfr[j], acc[i][j], 0, 0, 0);
    }
    // epilogue: C/D layout col=lane&15, row=quad*4+reg (m89/m91-verified)
#pragma unroll
    for (int i = 0; i < 4; i++) {
#pragma unroll
        for (int j = 0; j < 4; j++) {
#pragma unroll
            for (int r = 0; r < 4; r++) {
                int row = m0 + wm * 64 + i * 16 + quad * 4 + r;
                int col = n0 + wn * 64 + j * 16 + qr;
                size_t idx = (size_t)row * N + col;
                float v = acc[i][j][r];
                if (EPI == 0)      ((float*)OUT)[idx] = v;
                else if (EPI == 1) ((unsigned short*)OUT)[idx] = f2b(v);
                else if (EPI == 2) ((float*)OUT)[idx] = RES[idx] + v;
                else {
                    float g = 0.5f * v * (1.0f + erff(v * 0.70710678118f));
                    ((unsigned short*)OUT)[idx] = f2b(g);
                }
            }
        }
    }
}

// ---------- MFMA causal flash attention, K-chunk=128 ----------
// qkv bf16 [4096][3072] (q|k|v blocks of 1024 cols), out bf16 [4096][1024]
// Block: one head, 64 q-rows; 4 waves x 16 q-rows; 128 keys per barrier-triple.
__global__ __launch_bounds__(256) void k_attn(
        const unsigned short* __restrict__ qkv, unsigned short* __restrict__ out) {
    __shared__ unsigned short Ks[128][72];      // K rows (Q staged here first)
    __shared__ unsigned short Vt[64][132];      // [dim][key 0..127]
    __shared__ unsigned short Ps[4][16][132];   // per wave [q][key 0..127]

    int l = blockIdx.x;                // 0..1023; big qb dispatched first
    int h = l & 15;
    int qb = 63 - (l >> 4);
    int q0 = qb * 64;

    int tid = threadIdx.x;
    int wave = tid >> 6, lane = tid & 63;
    int lane16 = lane & 15, quad = lane >> 4;

    // ---- stage Q through Ks rows 0..63, read loop-invariant A-frags ----
    {
        int srow = tid >> 2, sc0 = (tid & 3) * 16;
        size_t base = (size_t)(q0 + srow) * 3072 + h * 64 + sc0;
        *(uint4*)&Ks[srow][sc0]     = *(const uint4*)&qkv[base];
        *(uint4*)&Ks[srow][sc0 + 8] = *(const uint4*)&qkv[base + 8];
    }
    __syncthreads();
    short8 aq0 = *(const short8*)&Ks[wave * 16 + lane16][quad * 8];
    short8 aq1 = *(const short8*)&Ks[wave * 16 + lane16][32 + quad * 8];

    f32x4 Oacc[4] = {};                // lane holds O[q=quad*4+r][d=dt*16+lane16]
    float m_i[4], l_i[4];
#pragma unroll
    for (int r = 0; r < 4; r++) { m_i[r] = -__builtin_inff(); l_i[r] = 0.0f; }

    for (int kc = 0; kc <= qb; kc += 2) {      // 128 keys per iteration
        __syncthreads();   // prev-iter LDS reads done (covers Q-frag reads at kc=0)
        {   // stage 128 K rows x 64 dims (coalesced b128)
            int srow = tid >> 1, c0 = (tid & 1) * 32;
            size_t base = (size_t)(kc * 64 + srow) * 3072 + 1024 + h * 64 + c0;
            *(uint4*)&Ks[srow][c0]      = *(const uint4*)&qkv[base];
            *(uint4*)&Ks[srow][c0 + 8]  = *(const uint4*)&qkv[base + 8];
            *(uint4*)&Ks[srow][c0 + 16] = *(const uint4*)&qkv[base + 16];
            *(uint4*)&Ks[srow][c0 + 24] = *(const uint4*)&qkv[base + 24];
        }
        {   // stage 128 V rows TRANSPOSED: wave = dim-group, lane = key
#pragma unroll
            for (int c2 = 0; c2 < 2; c2++) {
                size_t vbase = (size_t)((kc + c2) * 64 + lane) * 3072 + 2048 + h * 64 + wave * 16;
                __align__(16) unsigned short vs[16];
                *(uint4*)&vs[0] = *(const uint4*)&qkv[vbase];
                *(uint4*)&vs[8] = *(const uint4*)&qkv[vbase + 8];
#pragma unroll
                for (int j = 0; j < 16; j++) Vt[wave * 16 + j][c2 * 64 + lane] = vs[j];
            }
        }
        __syncthreads();

        // ---- S = Q K^T  (16q x 128k per wave) ----
        f32x4 sacc[8] = {};
#pragma unroll
        for (int kt = 0; kt < 8; kt++) {
            short8 bk0 = *(const short8*)&Ks[kt * 16 + lane16][quad * 8];
            short8 bk1 = *(const short8*)&Ks[kt * 16 + lane16][32 + quad * 8];
            sacc[kt] = __builtin_amdgcn_mfma_f32_16x16x32_bf16(aq0, bk0, sacc[kt], 0, 0, 0);
            sacc[kt] = __builtin_amdgcn_mfma_f32_16x16x32_bf16(aq1, bk1, sacc[kt], 0, 0, 0);
        }

        // ---- online softmax over 128 keys (C-layout: row=quad*4+r, col=kt*16+lane16)
#pragma unroll
        for (int r = 0; r < 4; r++) {
            int qrow = q0 + wave * 16 + quad * 4 + r;
            float sv[8], mx = -__builtin_inff();
#pragma unroll
            for (int kt = 0; kt < 8; kt++) {
                int key = kc * 64 + kt * 16 + lane16;
                sv[kt] = (key <= qrow) ? sacc[kt][r] * 0.125f : -__builtin_inff();
                mx = fmaxf(mx, sv[kt]);
            }
            mx = fmaxf(mx, __shfl_xor(mx, 1));
            mx = fmaxf(mx, __shfl_xor(mx, 2));
            mx = fmaxf(mx, __shfl_xor(mx, 4));
            mx = fmaxf(mx, __shfl_xor(mx, 8));
            float mn = fmaxf(m_i[r], mx);
            float alpha = __expf(m_i[r] - mn);   // first iter: exp(-inf)=0
            float ls = 0.0f;
#pragma unroll
            for (int kt = 0; kt < 8; kt++) {
                float p = __expf(sv[kt] - mn);   // masked -> 0
                ls += p;
                Ps[wave][quad * 4 + r][kt * 16 + lane16] = f2b(p);
            }
            ls += __shfl_xor(ls, 1);
            ls += __shfl_xor(ls, 2);
            ls += __shfl_xor(ls, 4);
            ls += __shfl_xor(ls, 8);
            l_i[r] = l_i[r] * alpha + ls;
            m_i[r] = mn;
#pragma unroll
            for (int dt = 0; dt < 4; dt++) Oacc[dt][r] *= alpha;
        }
        __syncthreads();   // Ps visible before PV reads

        // ---- O += P V  (A=P rows, B=V^T rows, both key-contiguous) ----
#pragma unroll
        for (int s = 0; s < 4; s++) {
            short8 ap = *(const short8*)&Ps[wave][lane16][s * 32 + quad * 8];
#pragma unroll
            for (int dt = 0; dt < 4; dt++) {
                short8 bv = *(const short8*)&Vt[dt * 16 + lane16][s * 32 + quad * 8];
                Oacc[dt] = __builtin_amdgcn_mfma_f32_16x16x32_bf16(ap, bv, Oacc[dt], 0, 0, 0);
            }
        }
    }

    float invl[4];
#pragma unroll
    for (int r = 0; r < 4; r++) invl[r] = 1.0f / l_i[r];
#pragma unroll
    for (int dt = 0; dt < 4; dt++) {
#pragma unroll
        for (int r = 0; r < 4; r++) {
            int qrow = q0 + wave * 16 + quad * 4 + r;
            out[(size_t)qrow * 1024 + h * 64 + dt * 16 + lane16] = f2b(Oacc[dt][r] * invl[r]);
        }
    }
}

// ---------- launch ----------
extern "C" void kernel_launch(void* const* d_in, const int* in_sizes, int n_in,
                              void* d_out, int out_size, void* d_ws, size_t ws_size,
                              hipStream_t stream) {
    const float* x      = (const float*)d_in[0];
    const float* w_qkv  = (const float*)d_in[1];
    const float* w_attn = (const float*)d_in[2];
    const float* w_fc   = (const float*)d_in[3];
    const float* w_mlp  = (const float*)d_in[4];
    const float* ln1w   = (const float*)d_in[5];
    const float* ln2w   = (const float*)d_in[6];

    char* ws = (char*)d_ws;   // total 112 MB, no aliasing
    unsigned short* h      = (unsigned short*)(ws + 0);          //  8 MB
    unsigned short* wqkvT  = (unsigned short*)(ws + 8388608);    //  6 MB
    unsigned short* wattnT = (unsigned short*)(ws + 14680064);   //  2 MB
    unsigned short* wfcT   = (unsigned short*)(ws + 16777216);   //  8 MB
    unsigned short* wmlpT  = (unsigned short*)(ws + 25165824);   //  8 MB
    unsigned short* qkv    = (unsigned short*)(ws + 33554432);   // 24 MB
    unsigned short* attno  = (unsigned short*)(ws + 58720256);   //  8 MB
    float*          x2     = (float*)(ws + 67108864);            // 16 MB
    unsigned short* fcact  = (unsigned short*)(ws + 83886080);   // 32 MB
    float* outF = (float*)d_out;

    dim3 tb(32, 8);
    k_transpose_bf16<<<dim3(96, 32),  tb, 0, stream>>>(w_qkv,  wqkvT,  1024, 3072);
    k_transpose_bf16<<<dim3(32, 32),  tb, 0, stream>>>(w_attn, wattnT, 1024, 1024);
    k_transpose_bf16<<<dim3(128, 32), tb, 0, stream>>>(w_fc,   wfcT,   1024, 4096);
    k_transpose_bf16<<<dim3(32, 128), tb, 0, stream>>>(w_mlp,  wmlpT,  4096, 1024);

    k_layernorm<<<4096, 256, 0, stream>>>(x, ln1w, h);
    k_gemm_bt<1><<<dim3(24, 32), 256, 0, stream>>>(h, wqkvT, nullptr, qkv, 4096, 3072, 1024);
    k_attn<<<1024, 256, 0, stream>>>(qkv, attno);
    k_gemm_bt<2><<<dim3(8, 32),  256, 0, stream>>>(attno, wattnT, x, x2, 4096, 1024, 1024);
    k_layernorm<<<4096, 256, 0, stream>>>(x2, ln2w, h);
    k_gemm_bt<3><<<dim3(32, 32), 256, 0, stream>>>(h, wfcT, nullptr, fcact, 4096, 4096, 1024);
    k_gemm_bt<2><<<dim3(8, 32),  256, 0, stream>>>(fcact, wmlpT, x2, outF, 4096, 1024, 4096);
}

// Round 5
// 426.148 us; speedup vs baseline: 4.0313x; 1.1452x over previous
//
#include <hip/hip_runtime.h>
#include <cstdint>

// ---------- helpers ----------
typedef __attribute__((ext_vector_type(8))) short short8;   // 8 x bf16 (4 VGPRs)
typedef __attribute__((ext_vector_type(4))) float f32x4;

__device__ __forceinline__ float b2f(unsigned short u) {
    return __uint_as_float(((unsigned int)u) << 16);
}
__device__ __forceinline__ unsigned short f2b(float f) {   // RNE f32->bf16
    unsigned int u = __float_as_uint(f);
    u += 0x7FFFu + ((u >> 16) & 1u);
    return (unsigned short)(u >> 16);
}

// async global->LDS, 16B per lane; LDS dest is wave-uniform base + lane*16
__device__ __forceinline__ void gload_lds16(const unsigned short* g, unsigned short* l) {
    __builtin_amdgcn_global_load_lds(
        (const __attribute__((address_space(1))) uint32_t*)g,
        (__attribute__((address_space(3))) uint32_t*)l, 16, 0, 0);
}

// ---------- transpose + fp32->bf16 convert: w[K][N] -> wT[N][K] ----------
__global__ __launch_bounds__(256) void k_transpose_bf16(
        const float* __restrict__ w, unsigned short* __restrict__ wT, int K, int N) {
    __shared__ float tile[32][33];
    int n0 = blockIdx.x * 32, k0 = blockIdx.y * 32;
    int tx = threadIdx.x, ty = threadIdx.y;   // block (32,8)
#pragma unroll
    for (int i = 0; i < 4; i++)
        tile[ty + 8 * i][tx] = w[(size_t)(k0 + ty + 8 * i) * N + n0 + tx];
    __syncthreads();
#pragma unroll
    for (int i = 0; i < 4; i++)
        wT[(size_t)(n0 + ty + 8 * i) * K + k0 + tx] = f2b(tile[tx][ty + 8 * i]);
}

// ---------- layernorm (fp32 in, bf16 out), one row (C=1024) per block ----------
__global__ __launch_bounds__(256) void k_layernorm(
        const float* __restrict__ x, const float* __restrict__ w,
        unsigned short* __restrict__ out) {
    int row = blockIdx.x, tid = threadIdx.x;
    const float4* xr = (const float4*)(x + (size_t)row * 1024);
    float4 v = xr[tid];
    float s  = v.x + v.y + v.z + v.w;
    float ss = v.x * v.x + v.y * v.y + v.z * v.z + v.w * v.w;
#pragma unroll
    for (int off = 32; off >= 1; off >>= 1) {
        s  += __shfl_down(s, off);
        ss += __shfl_down(ss, off);
    }
    __shared__ float red[10];
    if ((tid & 63) == 0) { red[tid >> 6] = s; red[4 + (tid >> 6)] = ss; }
    __syncthreads();
    if (tid == 0) {
        float S  = red[0] + red[1] + red[2] + red[3];
        float SS = red[4] + red[5] + red[6] + red[7];
        float mu  = S * (1.0f / 1024.0f);
        float var = SS * (1.0f / 1024.0f) - mu * mu;
        red[8] = mu; red[9] = rsqrtf(var + 1e-5f);
    }
    __syncthreads();
    float mu = red[8], rs = red[9];
    float4 wv = ((const float4*)w)[tid];
    ushort4 pk;
    pk.x = f2b((v.x - mu) * rs * wv.x);
    pk.y = f2b((v.y - mu) * rs * wv.y);
    pk.z = f2b((v.z - mu) * rs * wv.z);
    pk.w = f2b((v.w - mu) * rs * wv.w);
    *(ushort4*)(out + (size_t)row * 1024 + tid * 4) = pk;
}

// ---------- bf16 MFMA GEMM: C[M][N] = A[M][K] @ BT[N][K]^T (+ epilogue) ----------
// BK=64, column-rotate LDS swizzle (conflict-free frag reads), global_load_lds.
// EPI: 0 = store f32, 1 = store bf16, 2 = RES + acc -> f32, 3 = gelu(acc) -> bf16
// TN: 128 (4 waves 64x64) or 64 (4 waves 32x64)
template <int EPI, int TN>
__global__ __launch_bounds__(256) void k_gemm_bt(
        const unsigned short* __restrict__ A, const unsigned short* __restrict__ BT,
        const float* __restrict__ RES, void* __restrict__ OUT,
        int M, int N, int K) {
    constexpr int MI = (TN == 128) ? 4 : 2;        // m-subtiles per wave
    __shared__ __align__(16) unsigned short As[128 * 64];
    __shared__ __align__(16) unsigned short Bs[TN * 64];
    int tid  = threadIdx.x;
    int lane = tid & 63, wave = tid >> 6;
    int quad = lane >> 4, qr = lane & 15;
    int wm_off = (TN == 128) ? (wave >> 1) * 64 : wave * 32;
    int wn_off = (TN == 128) ? (wave & 1) * 64 : 0;
    int m0 = blockIdx.y * 128, n0 = blockIdx.x * TN;
    // swizzle: logical col c of row r lives at lds col (c + 8*(r&7)) & 63
    int lrow = lane >> 3;                            // staging: row within 8-row group
    int gcol = 8 * (((lane & 7) - lrow) & 7);        // staging: source logical col
    int cswz[2];
#pragma unroll
    for (int kk = 0; kk < 2; kk++) cswz[kk] = 8 * (((kk * 4) + quad + (qr & 7)) & 7);
    f32x4 acc[MI][4] = {};
    for (int k0 = 0; k0 < K; k0 += 64) {
        __syncthreads();
#pragma unroll
        for (int t = 0; t < 4; t++) {                // A: 16 instrs, 4/wave
            int rowb = wave * 32 + t * 8;
            gload_lds16(&A[(size_t)(m0 + rowb + lrow) * K + k0 + gcol], &As[rowb * 64]);
        }
#pragma unroll
        for (int t = 0; t < TN / 32; t++) {          // B: TN/8 instrs
            int rowb = wave * (TN / 4) + t * 8;
            gload_lds16(&BT[(size_t)(n0 + rowb + lrow) * K + k0 + gcol], &Bs[rowb * 64]);
        }
        __syncthreads();
#pragma unroll
        for (int kk = 0; kk < 2; kk++) {
            short8 af[MI], bfr[4];
#pragma unroll
            for (int i = 0; i < MI; i++) af[i]  = *(const short8*)&As[(wm_off + i * 16 + qr) * 64 + cswz[kk]];
#pragma unroll
            for (int j = 0; j < 4; j++)  bfr[j] = *(const short8*)&Bs[(wn_off + j * 16 + qr) * 64 + cswz[kk]];
#pragma unroll
            for (int i = 0; i < MI; i++)
#pragma unroll
                for (int j = 0; j < 4; j++)
                    acc[i][j] = __builtin_amdgcn_mfma_f32_16x16x32_bf16(af[i], bfr[j], acc[i][j], 0, 0, 0);
        }
    }
    // epilogue: C/D layout col=lane&15, row=quad*4+reg
#pragma unroll
    for (int i = 0; i < MI; i++) {
#pragma unroll
        for (int j = 0; j < 4; j++) {
#pragma unroll
            for (int r = 0; r < 4; r++) {
                int row = m0 + wm_off + i * 16 + quad * 4 + r;
                int col = n0 + wn_off + j * 16 + qr;
                size_t idx = (size_t)row * N + col;
                float v = acc[i][j][r];
                if (EPI == 0)      ((float*)OUT)[idx] = v;
                else if (EPI == 1) ((unsigned short*)OUT)[idx] = f2b(v);
                else if (EPI == 2) ((float*)OUT)[idx] = RES[idx] + v;
                else {
                    // tanh-form GELU via exp2: g = v*t/(t+1), t = 2^(2u/ln2)
                    float u = v * fmaf(v * v, 0.035677408f, 0.79788456f);
                    float e = fminf(u * 2.885390082f, 80.0f);   // guard inf/inf
                    float t = exp2f(e);
                    float g = v * t / (t + 1.0f);
                    ((unsigned short*)OUT)[idx] = f2b(g);
                }
            }
        }
    }
}

// ---------- MFMA causal flash attention, K-chunk=128, static-max softmax ------
// qkv bf16 [4096][3072] (q|k|v blocks of 1024 cols), out bf16 [4096][1024]
__global__ __launch_bounds__(256) void k_attn(
        const unsigned short* __restrict__ qkv, unsigned short* __restrict__ out) {
    __shared__ unsigned short Ks[128][72];      // K rows (Q staged here first)
    __shared__ unsigned short Vt[64][136];      // [dim][key 0..127], b128-aligned rows
    __shared__ unsigned short Ps[4][16][136];   // per wave [q][key 0..127]

    const float C1 = 0.18033688f;   // 0.125 * log2(e)
    const float C2 = 5.77078016f;   // 4.0   * log2(e)  (static max m=4)

    int l = blockIdx.x;                // 0..1023; big qb dispatched first
    int h = l & 15;
    int qb = 63 - (l >> 4);
    int q0 = qb * 64;

    int tid = threadIdx.x;
    int wave = tid >> 6, lane = tid & 63;
    int lane16 = lane & 15, quad = lane >> 4;

    // ---- stage Q through Ks rows 0..63, read loop-invariant A-frags ----
    {
        int srow = tid >> 2, sc0 = (tid & 3) * 16;
        size_t base = (size_t)(q0 + srow) * 3072 + h * 64 + sc0;
        *(uint4*)&Ks[srow][sc0]     = *(const uint4*)&qkv[base];
        *(uint4*)&Ks[srow][sc0 + 8] = *(const uint4*)&qkv[base + 8];
    }
    __syncthreads();
    short8 aq0 = *(const short8*)&Ks[wave * 16 + lane16][quad * 8];
    short8 aq1 = *(const short8*)&Ks[wave * 16 + lane16][32 + quad * 8];

    f32x4 Oacc[4] = {};                // lane holds O[q=quad*4+r][d=dt*16+lane16]
    float l_part[4] = {0.f, 0.f, 0.f, 0.f};

    int vk = (lane & 31) * 2;          // V staging: even local key
    int d0 = wave * 16 + (lane >> 5) * 8;

    for (int kc = 0; kc <= qb; kc += 2) {      // 128 keys per iteration
        __syncthreads();   // prev-iter LDS reads done (covers Q-frag reads at kc=0)
        {   // stage 128 K rows x 64 dims (coalesced b128)
            int srow = tid >> 1, c0 = (tid & 1) * 32;
            size_t base = (size_t)(kc * 64 + srow) * 3072 + 1024 + h * 64 + c0;
            *(uint4*)&Ks[srow][c0]      = *(const uint4*)&qkv[base];
            *(uint4*)&Ks[srow][c0 + 8]  = *(const uint4*)&qkv[base + 8];
            *(uint4*)&Ks[srow][c0 + 16] = *(const uint4*)&qkv[base + 16];
            *(uint4*)&Ks[srow][c0 + 24] = *(const uint4*)&qkv[base + 24];
        }
        {   // stage 128 V rows TRANSPOSED, key-pairs packed as b32 writes
#pragma unroll
            for (int c2 = 0; c2 < 2; c2++) {
                size_t vb = (size_t)((kc + c2) * 64 + vk) * 3072 + 2048 + h * 64 + d0;
                uint4 ve = *(const uint4*)&qkv[vb];
                uint4 vo = *(const uint4*)&qkv[vb + 3072];
                const unsigned short* pe = (const unsigned short*)&ve;
                const unsigned short* po = (const unsigned short*)&vo;
#pragma unroll
                for (int j = 0; j < 8; j++)
                    *(uint32_t*)&Vt[d0 + j][c2 * 64 + vk] =
                        (uint32_t)pe[j] | ((uint32_t)po[j] << 16);
            }
        }
        __syncthreads();

        // ---- S = Q K^T  (16q x 128k per wave) ----
        f32x4 sacc[8] = {};
#pragma unroll
        for (int kt = 0; kt < 8; kt++) {
            short8 bk0 = *(const short8*)&Ks[kt * 16 + lane16][quad * 8];
            short8 bk1 = *(const short8*)&Ks[kt * 16 + lane16][32 + quad * 8];
            sacc[kt] = __builtin_amdgcn_mfma_f32_16x16x32_bf16(aq0, bk0, sacc[kt], 0, 0, 0);
            sacc[kt] = __builtin_amdgcn_mfma_f32_16x16x32_bf16(aq1, bk1, sacc[kt], 0, 0, 0);
        }

        // ---- static-max softmax: p = 2^(s*C1 - C2); mask only on last chunk ----
        bool domask = (kc + 2 > qb);   // wave-uniform
#pragma unroll
        for (int r = 0; r < 4; r++) {
            int qrow = q0 + wave * 16 + quad * 4 + r;
#pragma unroll
            for (int kt = 0; kt < 8; kt++) {
                float s = sacc[kt][r];
                if (domask) {
                    int key = kc * 64 + kt * 16 + lane16;
                    s = (key <= qrow) ? s : -__builtin_inff();
                }
                float p = exp2f(fmaf(s, C1, -C2));   // masked -> 0
                l_part[r] += p;
                Ps[wave][quad * 4 + r][kt * 16 + lane16] = f2b(p);
            }
        }
        __syncthreads();   // Ps visible before PV reads

        // ---- O += P V  (A=P rows, B=V^T rows, both key-contiguous) ----
#pragma unroll
        for (int s = 0; s < 4; s++) {
            short8 ap = *(const short8*)&Ps[wave][lane16][s * 32 + quad * 8];
#pragma unroll
            for (int dt = 0; dt < 4; dt++) {
                short8 bv = *(const short8*)&Vt[dt * 16 + lane16][s * 32 + quad * 8];
                Oacc[dt] = __builtin_amdgcn_mfma_f32_16x16x32_bf16(ap, bv, Oacc[dt], 0, 0, 0);
            }
        }
    }

    // deferred l reduction (sum over lane16 group) + output
    float invl[4];
#pragma unroll
    for (int r = 0; r < 4; r++) {
        float lf = l_part[r];
        lf += __shfl_xor(lf, 1);
        lf += __shfl_xor(lf, 2);
        lf += __shfl_xor(lf, 4);
        lf += __shfl_xor(lf, 8);
        invl[r] = 1.0f / lf;
    }
#pragma unroll
    for (int dt = 0; dt < 4; dt++) {
#pragma unroll
        for (int r = 0; r < 4; r++) {
            int qrow = q0 + wave * 16 + quad * 4 + r;
            out[(size_t)qrow * 1024 + h * 64 + dt * 16 + lane16] = f2b(Oacc[dt][r] * invl[r]);
        }
    }
}

// ---------- launch ----------
extern "C" void kernel_launch(void* const* d_in, const int* in_sizes, int n_in,
                              void* d_out, int out_size, void* d_ws, size_t ws_size,
                              hipStream_t stream) {
    const float* x      = (const float*)d_in[0];
    const float* w_qkv  = (const float*)d_in[1];
    const float* w_attn = (const float*)d_in[2];
    const float* w_fc   = (const float*)d_in[3];
    const float* w_mlp  = (const float*)d_in[4];
    const float* ln1w   = (const float*)d_in[5];
    const float* ln2w   = (const float*)d_in[6];

    char* ws = (char*)d_ws;   // total 112 MB, no aliasing
    unsigned short* h      = (unsigned short*)(ws + 0);          //  8 MB
    unsigned short* wqkvT  = (unsigned short*)(ws + 8388608);    //  6 MB
    unsigned short* wattnT = (unsigned short*)(ws + 14680064);   //  2 MB
    unsigned short* wfcT   = (unsigned short*)(ws + 16777216);   //  8 MB
    unsigned short* wmlpT  = (unsigned short*)(ws + 25165824);   //  8 MB
    unsigned short* qkv    = (unsigned short*)(ws + 33554432);   // 24 MB
    unsigned short* attno  = (unsigned short*)(ws + 58720256);   //  8 MB
    float*          x2     = (float*)(ws + 67108864);            // 16 MB
    unsigned short* fcact  = (unsigned short*)(ws + 83886080);   // 32 MB
    float* outF = (float*)d_out;

    dim3 tb(32, 8);
    k_transpose_bf16<<<dim3(96, 32),  tb, 0, stream>>>(w_qkv,  wqkvT,  1024, 3072);
    k_transpose_bf16<<<dim3(32, 32),  tb, 0, stream>>>(w_attn, wattnT, 1024, 1024);
    k_transpose_bf16<<<dim3(128, 32), tb, 0, stream>>>(w_fc,   wfcT,   1024, 4096);
    k_transpose_bf16<<<dim3(32, 128), tb, 0, stream>>>(w_mlp,  wmlpT,  4096, 1024);

    k_layernorm<<<4096, 256, 0, stream>>>(x, ln1w, h);
    k_gemm_bt<1, 128><<<dim3(24, 32), 256, 0, stream>>>(h, wqkvT, nullptr, qkv, 4096, 3072, 1024);
    k_attn<<<1024, 256, 0, stream>>>(qkv, attno);
    k_gemm_bt<2, 64><<<dim3(16, 32), 256, 0, stream>>>(attno, wattnT, x, x2, 4096, 1024, 1024);
    k_layernorm<<<4096, 256, 0, stream>>>(x2, ln2w, h);
    k_gemm_bt<3, 128><<<dim3(32, 32), 256, 0, stream>>>(h, wfcT, nullptr, fcact, 4096, 4096, 1024);
    k_gemm_bt<2, 64><<<dim3(16, 32), 256, 0, stream>>>(fcact, wmlpT, x2, outF, 4096, 1024, 4096);
}